// Round 3
// baseline (326.042 us; speedup 1.0000x reference)
//
#include <hip/hip_runtime.h>
#include <hip/hip_bf16.h>

// SiLU-and-mul: x shape (4, 2048, 32768) fp32; gate = x[..., :16384],
// up = x[..., 16384:]; out = silu(gate) * up, shape (4, 2048, 16384) fp32.
// Memory-bound: 1.074 GB read + 0.537 GB write -> ~255 us at 6.3 TB/s.
// R1: 315.9 us (5.10 TB/s). This round: nontemporal load/store (nt cache
// policy, use-once streams) + x4 unroll for load MLP.
// R2 was an infra failure (container unresponsive) — same kernel resubmitted.

#define D_HALF   16384            // half of last dim (floats)
#define D4_HALF  (D_HALF / 4)     // 4096 float4 per half-row
#define D4_FULL  (D4_HALF * 2)    // 8192 float4 per input row

typedef float f4 __attribute__((ext_vector_type(4)));

__device__ __forceinline__ float silu(float x) {
    // x * sigmoid(x) = x / (1 + e^-x). Large -x: expf -> inf -> 0. Safe.
    return x / (1.0f + expf(-x));
}

__global__ void SiluAndMul_kernel(const f4* __restrict__ x,
                                  f4* __restrict__ out,
                                  long long n4) {
    const long long stride = (long long)gridDim.x * blockDim.x;
    long long i = (long long)blockIdx.x * blockDim.x + threadIdx.x;
#pragma unroll 4
    for (; i < n4; i += stride) {
        long long row = i >> 12;           // i / D4_HALF
        long long col = i & (D4_HALF - 1); // i % D4_HALF
        long long g_idx = row * D4_FULL + col;
        f4 g = __builtin_nontemporal_load(&x[g_idx]);
        f4 u = __builtin_nontemporal_load(&x[g_idx + D4_HALF]);
        f4 r;
        r.x = silu(g.x) * u.x;
        r.y = silu(g.y) * u.y;
        r.z = silu(g.z) * u.z;
        r.w = silu(g.w) * u.w;
        __builtin_nontemporal_store(r, &out[i]);
    }
}

extern "C" void kernel_launch(void* const* d_in, const int* in_sizes, int n_in,
                              void* d_out, int out_size, void* d_ws, size_t ws_size,
                              hipStream_t stream) {
    const f4* x = (const f4*)d_in[0];
    f4* out = (f4*)d_out;
    long long n4 = (long long)out_size / 4;   // 33,554,432 float4 outputs

    const int block = 256;
    // 2048 blocks = 8 blocks/CU x 256 CU x 4 waves = full 32 waves/CU.
    // n4 / (2048*256) = 64 iterations/thread exactly (no ragged tail).
    int grid = 2048;
    long long need = (n4 + block - 1) / block;
    if (need < grid) grid = (int)need;

    SiluAndMul_kernel<<<grid, block, 0, stream>>>(x, out, n4);
}

// Round 4
// 307.093 us; speedup vs baseline: 1.0617x; 1.0617x over previous
//
#include <hip/hip_runtime.h>
#include <hip/hip_bf16.h>

// SiLU-and-mul: x shape (4, 2048, 32768) fp32; gate = x[..., :16384],
// up = x[..., 16384:]; out = silu(gate) * up, shape (4, 2048, 16384) fp32.
// Memory-bound: 1.074 GB read + 0.537 GB write.
// R1: 316 us (5.10 TB/s) full-occupancy grid-stride.
// R3: 326 us nt+unroll4 — nt reverted.
// R4: low-occupancy (2 blocks/CU) block-contiguous streams, mimicking the
//     6.5 TB/s fillBuffer profile; manual 2x load batching; raw v_rcp_f32.

#define D4_HALF  4096             // float4 per half-row (16384 floats / 4)
#define D4_FULL  8192             // float4 per input row
#define BLOCK    256
#define GRID     512              // 2 blocks/CU on 256 CUs
#define ITER     256              // 33554432 f4 / (512*256) exactly

typedef float f4 __attribute__((ext_vector_type(4)));

__device__ __forceinline__ float silu(float x) {
    // x * sigmoid(x) = x * rcp(1 + e^-x). v_rcp_f32 is ~22.5-bit accurate:
    // abs err ~2e-5 on O(100) outputs, far under the 0.335 threshold.
    // Large -x: expf->inf, rcp->0, result 0. Large +x: rcp(1)=1, result x.
    return x * __builtin_amdgcn_rcpf(1.0f + expf(-x));
}

__device__ __forceinline__ f4 silu_mul(f4 g, f4 u) {
    f4 r;
    r.x = silu(g.x) * u.x;
    r.y = silu(g.y) * u.y;
    r.z = silu(g.z) * u.z;
    r.w = silu(g.w) * u.w;
    return r;
}

__global__ void __launch_bounds__(BLOCK)
SiluAndMul_kernel(const f4* __restrict__ x, f4* __restrict__ out) {
    // Block b owns output f4 range [b*BLOCK*ITER, (b+1)*BLOCK*ITER):
    // a contiguous 1 MB output chunk streamed wave-coalesced, 2 iters at a time.
    long long base = (long long)blockIdx.x * (BLOCK * ITER) + threadIdx.x;
#pragma unroll 2
    for (int j = 0; j < ITER; j += 2) {
        long long i0 = base + (long long)j * BLOCK;
        long long i1 = i0 + BLOCK;
        long long r0 = i0 >> 12, c0 = i0 & (D4_HALF - 1);
        long long r1 = i1 >> 12, c1 = i1 & (D4_HALF - 1);
        long long gi0 = r0 * D4_FULL + c0;
        long long gi1 = r1 * D4_FULL + c1;
        // Issue all 4 loads before any compute/store (4 KB in flight/wave).
        f4 g0 = x[gi0];
        f4 u0 = x[gi0 + D4_HALF];
        f4 g1 = x[gi1];
        f4 u1 = x[gi1 + D4_HALF];
        out[i0] = silu_mul(g0, u0);
        out[i1] = silu_mul(g1, u1);
    }
}

extern "C" void kernel_launch(void* const* d_in, const int* in_sizes, int n_in,
                              void* d_out, int out_size, void* d_ws, size_t ws_size,
                              hipStream_t stream) {
    const f4* x = (const f4*)d_in[0];
    f4* out = (f4*)d_out;
    // out_size = 134217728 floats = 33554432 f4 = GRID*BLOCK*ITER exactly.
    SiluAndMul_kernel<<<GRID, BLOCK, 0, stream>>>(x, out);
}

// Round 5
// 294.845 us; speedup vs baseline: 1.1058x; 1.0415x over previous
//
#include <hip/hip_runtime.h>
#include <hip/hip_bf16.h>

// SiLU-and-mul: x shape (4, 2048, 32768) fp32; gate = x[..., :16384],
// up = x[..., 16384:]; out = silu(gate) * up, shape (4, 2048, 16384) fp32.
// Memory-bound: 1.074 GB read + 0.537 GB write.
// R1: 316 us (5.10 TB/s) full-occupancy grid-stride.
// R3: 326 us nt+unroll4 — reverted.
// R4: 307 us (5.25 TB/s) 2 blocks/CU, block-contiguous 1MB chunks.
// R5: explicit register double-buffer: prefetch next 4-f4 batch (8 loads,
//     8 KB/wave) before computing current -> loads always in flight,
//     counted vmcnt instead of drain-to-0. 32-bit index math.

#define D4_HALF  4096             // float4 per half-row (16384 floats / 4)
#define D4_FULL  8192             // float4 per input row
#define BLOCK    256
#define GRID     512              // 2 blocks/CU on 256 CUs
#define ITER     256              // 33554432 f4 / (512*256) exactly
#define BATCH    4                // f4 per thread per batch
#define NBATCH   (ITER / BATCH)   // 64

typedef float f4 __attribute__((ext_vector_type(4)));

__device__ __forceinline__ float silu(float x) {
    // x * sigmoid(x) = x * rcp(1 + e^-x). v_rcp_f32 ~22.5-bit accurate,
    // far under the 0.335 bf16-floor threshold. Large -x: exp->inf, rcp->0.
    return x * __builtin_amdgcn_rcpf(1.0f + expf(-x));
}

struct Batch { f4 g[BATCH]; f4 u[BATCH]; };

__device__ __forceinline__ Batch load_batch(const f4* __restrict__ x,
                                            int base, int b) {
    Batch r;
#pragma unroll
    for (int k = 0; k < BATCH; ++k) {
        int i = base + (b * BATCH + k) * BLOCK;      // output f4 index
        int gi = (i >> 12) * D4_FULL + (i & (D4_HALF - 1));
        r.g[k] = x[gi];
        r.u[k] = x[gi + D4_HALF];
    }
    return r;
}

__device__ __forceinline__ void store_batch(f4* __restrict__ out,
                                            int base, int b, const Batch& t) {
#pragma unroll
    for (int k = 0; k < BATCH; ++k) {
        f4 r;
        r.x = silu(t.g[k].x) * t.u[k].x;
        r.y = silu(t.g[k].y) * t.u[k].y;
        r.z = silu(t.g[k].z) * t.u[k].z;
        r.w = silu(t.g[k].w) * t.u[k].w;
        out[base + (b * BATCH + k) * BLOCK] = r;
    }
}

__global__ void __launch_bounds__(BLOCK)
SiluAndMul_kernel(const f4* __restrict__ x, f4* __restrict__ out) {
    // Block owns a contiguous 1 MB output chunk; explicit 2-deep register
    // pipeline with static A/B names (no runtime-indexed arrays — scratch).
    int base = blockIdx.x * (BLOCK * ITER) + threadIdx.x;
    Batch A = load_batch(x, base, 0);
#pragma unroll 1
    for (int b = 0; b < NBATCH; b += 2) {
        Batch B = load_batch(x, base, b + 1);   // issue before waiting on A
        store_batch(out, base, b, A);
        if (b + 2 < NBATCH) A = load_batch(x, base, b + 2);
        store_batch(out, base, b + 1, B);
    }
}

extern "C" void kernel_launch(void* const* d_in, const int* in_sizes, int n_in,
                              void* d_out, int out_size, void* d_ws, size_t ws_size,
                              hipStream_t stream) {
    const f4* x = (const f4*)d_in[0];
    f4* out = (f4*)d_out;
    // out_size = 134217728 floats = 33554432 f4 = GRID*BLOCK*ITER exactly.
    SiluAndMul_kernel<<<GRID, BLOCK, 0, stream>>>(x, out);
}

// Round 6
// 292.873 us; speedup vs baseline: 1.1133x; 1.0067x over previous
//
#include <hip/hip_runtime.h>

// SiLU-and-mul: x shape (4, 2048, 32768) fp32; gate = x[..., :16384],
// up = x[..., 16384:]; out = silu(gate) * up, shape (4, 2048, 16384) fp32.
// Memory-bound: 1.074 GB read + 0.537 GB write.
// R1: 316 us (5.10 TB/s) full-occupancy grid-stride.
// R3: 326 us nt+unroll4 — reverted.
// R4: 307 us (5.25 TB/s) 2 blocks/CU, block-contiguous 1MB chunks.
// R5: 295 us (5.46 TB/s) register double-buffer (8KB/wave in flight).
// R6: 4 blocks/CU (16 waves/CU) for compute-overlap capacity + __expf
//     (bare v_exp_f32 instead of libm fixup path).

#define D4_HALF  4096             // float4 per half-row (16384 floats / 4)
#define D4_FULL  8192             // float4 per input row
#define BLOCK    256
#define GRID     1024             // 4 blocks/CU on 256 CUs = 16 waves/CU
#define ITER     128              // 33554432 f4 / (1024*256) exactly
#define BATCH    4                // f4 per thread per batch
#define NBATCH   (ITER / BATCH)   // 32

typedef float f4 __attribute__((ext_vector_type(4)));

__device__ __forceinline__ float silu(float x) {
    // x * sigmoid(x) = x * rcp(1 + e^-x). __expf -> v_mul+v_exp_f32;
    // v_rcp_f32 ~22.5-bit. abs err ~1e-5 on O(10) outputs << 0.335 threshold.
    // Large -x: exp->inf, rcp->0 -> 0. Large +x: rcp(1)=1 -> x. Safe.
    return x * __builtin_amdgcn_rcpf(1.0f + __expf(-x));
}

struct Batch { f4 g[BATCH]; f4 u[BATCH]; };

__device__ __forceinline__ Batch load_batch(const f4* __restrict__ x,
                                            int base, int b) {
    Batch r;
#pragma unroll
    for (int k = 0; k < BATCH; ++k) {
        int i = base + (b * BATCH + k) * BLOCK;      // output f4 index
        int gi = (i >> 12) * D4_FULL + (i & (D4_HALF - 1));
        r.g[k] = x[gi];
        r.u[k] = x[gi + D4_HALF];
    }
    return r;
}

__device__ __forceinline__ void store_batch(f4* __restrict__ out,
                                            int base, int b, const Batch& t) {
#pragma unroll
    for (int k = 0; k < BATCH; ++k) {
        f4 r;
        r.x = silu(t.g[k].x) * t.u[k].x;
        r.y = silu(t.g[k].y) * t.u[k].y;
        r.z = silu(t.g[k].z) * t.u[k].z;
        r.w = silu(t.g[k].w) * t.u[k].w;
        out[base + (b * BATCH + k) * BLOCK] = r;
    }
}

__global__ void __launch_bounds__(BLOCK)
SiluAndMul_kernel(const f4* __restrict__ x, f4* __restrict__ out) {
    // Block owns a contiguous 512 KB output chunk; explicit 2-deep register
    // pipeline with static A/B names (no runtime-indexed arrays — scratch).
    int base = blockIdx.x * (BLOCK * ITER) + threadIdx.x;
    Batch A = load_batch(x, base, 0);
#pragma unroll 1
    for (int b = 0; b < NBATCH; b += 2) {
        Batch B = load_batch(x, base, b + 1);   // issue before waiting on A
        store_batch(out, base, b, A);
        if (b + 2 < NBATCH) A = load_batch(x, base, b + 2);
        store_batch(out, base, b + 1, B);
    }
}

extern "C" void kernel_launch(void* const* d_in, const int* in_sizes, int n_in,
                              void* d_out, int out_size, void* d_ws, size_t ws_size,
                              hipStream_t stream) {
    const f4* x = (const f4*)d_in[0];
    f4* out = (f4*)d_out;
    // out_size = 134217728 floats = 33554432 f4 = GRID*BLOCK*ITER exactly.
    SiluAndMul_kernel<<<GRID, BLOCK, 0, stream>>>(x, out);
}